// Round 1
// baseline (407.079 us; speedup 1.0000x reference)
//
#include <hip/hip_runtime.h>

// 3D trilinear warp (grid_sample, align_corners=True equivalent, zeros padding)
// src:  [B=2, C=1, D=160, H=192, W=224] f32
// flow: [B=2, 3,   D,     H,     W    ] f32  (d,h,w voxel displacements)
// out:  [B=2, C=1, D,     H,     W    ] f32

#define DD 160
#define HH 192
#define WW 224
#define BB 2
constexpr int DHW = DD * HH * WW;          // 6,881,280 (divisible by 4)
constexpr int TOTAL4 = BB * DHW / 4;       // groups of 4 voxels

__device__ __forceinline__ float trilerp(const float* __restrict__ sbase,
                                         float cd, float ch, float cw) {
    float d0f = floorf(cd), h0f = floorf(ch), w0f = floorf(cw);
    float fd = cd - d0f, fh = ch - h0f, fw = cw - w0f;
    int d0 = (int)d0f, h0 = (int)h0f, w0 = (int)w0f;

    float acc = 0.0f;
    #pragma unroll
    for (int dd = 0; dd < 2; ++dd) {
        int id = d0 + dd;
        if ((unsigned)id >= (unsigned)DD) continue;
        float wd = dd ? fd : 1.0f - fd;
        #pragma unroll
        for (int hh = 0; hh < 2; ++hh) {
            int ih = h0 + hh;
            if ((unsigned)ih >= (unsigned)HH) continue;
            float wh = hh ? fh : 1.0f - fh;
            float wdh = wd * wh;
            int rowoff = (id * HH + ih) * WW;
            #pragma unroll
            for (int ww = 0; ww < 2; ++ww) {
                int iw = w0 + ww;
                if ((unsigned)iw >= (unsigned)WW) continue;
                float wwt = ww ? fw : 1.0f - fw;
                acc += sbase[rowoff + iw] * (wdh * wwt);
            }
        }
    }
    return acc;
}

__global__ __launch_bounds__(256) void warp3d_kernel(
    const float* __restrict__ src, const float* __restrict__ flow,
    float* __restrict__ out) {
    int i4 = blockIdx.x * blockDim.x + threadIdx.x;
    if (i4 >= TOTAL4) return;
    int i = i4 * 4;                 // first of 4 consecutive voxels
    int b = i / DHW;
    int s = i - b * DHW;            // flat index within [D,H,W]

    const float* fbase = flow + (size_t)b * 3 * DHW;
    const float* sbase = src + (size_t)b * DHW;

    float4 fld = *reinterpret_cast<const float4*>(fbase + s);
    float4 flh = *reinterpret_cast<const float4*>(fbase + DHW + s);
    float4 flw = *reinterpret_cast<const float4*>(fbase + 2 * DHW + s);

    float fdv[4] = {fld.x, fld.y, fld.z, fld.w};
    float fhv[4] = {flh.x, flh.y, flh.z, flh.w};
    float fwv[4] = {flw.x, flw.y, flw.z, flw.w};

    float res[4];
    #pragma unroll
    for (int k = 0; k < 4; ++k) {
        int sk = s + k;
        int w  = sk % WW;
        int t  = sk / WW;
        int h  = t % HH;
        int d  = t / HH;
        float cd = (float)d + fdv[k];
        float ch = (float)h + fhv[k];
        float cw = (float)w + fwv[k];
        res[k] = trilerp(sbase, cd, ch, cw);
    }

    float4 o = make_float4(res[0], res[1], res[2], res[3]);
    *reinterpret_cast<float4*>(out + (size_t)i) = o;
}

extern "C" void kernel_launch(void* const* d_in, const int* in_sizes, int n_in,
                              void* d_out, int out_size, void* d_ws, size_t ws_size,
                              hipStream_t stream) {
    const float* src  = (const float*)d_in[0];
    const float* flow = (const float*)d_in[1];
    float* out = (float*)d_out;

    int blocks = (TOTAL4 + 255) / 256;
    warp3d_kernel<<<blocks, 256, 0, stream>>>(src, flow, out);
}

// Round 2
// 317.238 us; speedup vs baseline: 1.2832x; 1.2832x over previous
//
#include <hip/hip_runtime.h>

// 3D trilinear warp (grid_sample, align_corners=True equivalent, zeros padding)
// src:  [B=2, C=1, D=160, H=192, W=224] f32
// flow: [B=2, 3,   D,     H,     W    ] f32  (d,h,w voxel displacements)
// out:  [B=2, C=1, D,     H,     W    ] f32

#define DD 160
#define HH 192
#define WW 224
#define BB 2
constexpr int DHW = DD * HH * WW;          // 6,881,280 (divisible by 4)
constexpr int TOTAL4 = BB * DHW / 4;       // groups of 4 voxels
constexpr int BLOCK = 256;
constexpr int NWG = TOTAL4 / BLOCK;        // 13440, divisible by 8
constexpr int NXCD = 8;
constexpr int CHUNK = NWG / NXCD;          // 1680 blocks per XCD chunk

__device__ __forceinline__ float trilerp(const float* __restrict__ sbase,
                                         float cd, float ch, float cw) {
    float d0f = floorf(cd), h0f = floorf(ch), w0f = floorf(cw);
    float fd = cd - d0f, fh = ch - h0f, fw = cw - w0f;
    int d0 = (int)d0f, h0 = (int)h0f, w0 = (int)w0f;

    float acc = 0.0f;
    #pragma unroll
    for (int dd = 0; dd < 2; ++dd) {
        int id = d0 + dd;
        if ((unsigned)id >= (unsigned)DD) continue;
        float wd = dd ? fd : 1.0f - fd;
        #pragma unroll
        for (int hh = 0; hh < 2; ++hh) {
            int ih = h0 + hh;
            if ((unsigned)ih >= (unsigned)HH) continue;
            float wh = hh ? fh : 1.0f - fh;
            float wdh = wd * wh;
            int rowoff = (id * HH + ih) * WW;
            #pragma unroll
            for (int ww = 0; ww < 2; ++ww) {
                int iw = w0 + ww;
                if ((unsigned)iw >= (unsigned)WW) continue;
                float wwt = ww ? fw : 1.0f - fw;
                acc += sbase[rowoff + iw] * (wdh * wwt);
            }
        }
    }
    return acc;
}

__global__ __launch_bounds__(256) void warp3d_kernel(
    const float* __restrict__ src, const float* __restrict__ flow,
    float* __restrict__ out) {
    // XCD-aware swizzle: consecutive work chunks stay on one XCD so the
    // src slab (+halo) lives in that XCD's private 4 MB L2.
    int bid = blockIdx.x;                 // 0..NWG-1, dispatched i%8 -> XCD
    int xcd = bid % NXCD;
    int idx = bid / NXCD;
    int wg  = xcd * CHUNK + idx;          // contiguous chunk per XCD

    int i4 = wg * BLOCK + threadIdx.x;
    int i = i4 * 4;                 // first of 4 consecutive voxels
    int b = i / DHW;
    int s = i - b * DHW;            // flat index within [D,H,W]

    const float* fbase = flow + (size_t)b * 3 * DHW;
    const float* sbase = src + (size_t)b * DHW;

    float4 fld = *reinterpret_cast<const float4*>(fbase + s);
    float4 flh = *reinterpret_cast<const float4*>(fbase + DHW + s);
    float4 flw = *reinterpret_cast<const float4*>(fbase + 2 * DHW + s);

    float fdv[4] = {fld.x, fld.y, fld.z, fld.w};
    float fhv[4] = {flh.x, flh.y, flh.z, flh.w};
    float fwv[4] = {flw.x, flw.y, flw.z, flw.w};

    float res[4];
    #pragma unroll
    for (int k = 0; k < 4; ++k) {
        int sk = s + k;
        int w  = sk % WW;
        int t  = sk / WW;
        int h  = t % HH;
        int d  = t / HH;
        float cd = (float)d + fdv[k];
        float ch = (float)h + fhv[k];
        float cw = (float)w + fwv[k];
        res[k] = trilerp(sbase, cd, ch, cw);
    }

    float4 o = make_float4(res[0], res[1], res[2], res[3]);
    *reinterpret_cast<float4*>(out + (size_t)i) = o;
}

extern "C" void kernel_launch(void* const* d_in, const int* in_sizes, int n_in,
                              void* d_out, int out_size, void* d_ws, size_t ws_size,
                              hipStream_t stream) {
    const float* src  = (const float*)d_in[0];
    const float* flow = (const float*)d_in[1];
    float* out = (float*)d_out;

    warp3d_kernel<<<NWG, BLOCK, 0, stream>>>(src, flow, out);
}

// Round 3
// 211.500 us; speedup vs baseline: 1.9247x; 1.4999x over previous
//
#include <hip/hip_runtime.h>

// 3D trilinear warp (grid_sample, align_corners=True equivalent, zeros padding)
// src:  [B=2, C=1, D=160, H=192, W=224] f32
// flow: [B=2, 3,   D,     H,     W    ] f32  (d,h,w voxel displacements)
// out:  [B=2, C=1, D,     H,     W    ] f32

#define DD 160
#define HH 192
#define WW 224
#define BB 2
constexpr int DHW = DD * HH * WW;          // 6,881,280 (divisible by 4)
constexpr int TOTAL4 = BB * DHW / 4;       // groups of 4 voxels
constexpr int BLOCK = 256;
constexpr int NWG = TOTAL4 / BLOCK;        // 13440, divisible by 8
constexpr int NXCD = 8;
constexpr int CHUNK = NWG / NXCD;          // 1680 blocks per XCD chunk

// Branchless trilinear tap: validity folded into per-dimension weights,
// loads from clamped indices issued unconditionally (8 loads batch under
// one waitcnt instead of 8 serial exec-mask-branch chains).
__device__ __forceinline__ float trilerp(const float* __restrict__ sbase,
                                         float cd, float ch, float cw) {
    float d0f = floorf(cd), h0f = floorf(ch), w0f = floorf(cw);
    float fd = cd - d0f, fh = ch - h0f, fw = cw - w0f;
    int d0 = (int)d0f, h0 = (int)h0f, w0 = (int)w0f;
    int d1 = d0 + 1, h1 = h0 + 1, w1 = w0 + 1;

    float wd0 = (1.0f - fd) * ((unsigned)d0 < (unsigned)DD ? 1.0f : 0.0f);
    float wd1 = fd          * ((unsigned)d1 < (unsigned)DD ? 1.0f : 0.0f);
    float wh0 = (1.0f - fh) * ((unsigned)h0 < (unsigned)HH ? 1.0f : 0.0f);
    float wh1 = fh          * ((unsigned)h1 < (unsigned)HH ? 1.0f : 0.0f);
    float ww0 = (1.0f - fw) * ((unsigned)w0 < (unsigned)WW ? 1.0f : 0.0f);
    float ww1 = fw          * ((unsigned)w1 < (unsigned)WW ? 1.0f : 0.0f);

    int d0c = min(max(d0, 0), DD - 1), d1c = min(max(d1, 0), DD - 1);
    int h0c = min(max(h0, 0), HH - 1), h1c = min(max(h1, 0), HH - 1);
    int w0c = min(max(w0, 0), WW - 1), w1c = min(max(w1, 0), WW - 1);

    const float* p00 = sbase + (d0c * HH + h0c) * WW;
    const float* p01 = sbase + (d0c * HH + h1c) * WW;
    const float* p10 = sbase + (d1c * HH + h0c) * WW;
    const float* p11 = sbase + (d1c * HH + h1c) * WW;

    float v000 = p00[w0c], v001 = p00[w1c];
    float v010 = p01[w0c], v011 = p01[w1c];
    float v100 = p10[w0c], v101 = p10[w1c];
    float v110 = p11[w0c], v111 = p11[w1c];

    return wd0 * (wh0 * (ww0 * v000 + ww1 * v001) +
                  wh1 * (ww0 * v010 + ww1 * v011)) +
           wd1 * (wh0 * (ww0 * v100 + ww1 * v101) +
                  wh1 * (ww0 * v110 + ww1 * v111));
}

__global__ __launch_bounds__(256) void warp3d_kernel(
    const float* __restrict__ src, const float* __restrict__ flow,
    float* __restrict__ out) {
    // XCD-aware swizzle: consecutive work chunks stay on one XCD so the
    // src slab (+halo) lives in that XCD's private 4 MB L2.
    int bid = blockIdx.x;                 // 0..NWG-1, dispatched i%8 -> XCD
    int xcd = bid % NXCD;
    int idx = bid / NXCD;
    int wg  = xcd * CHUNK + idx;          // contiguous chunk per XCD

    int i4 = wg * BLOCK + threadIdx.x;
    int i = i4 * 4;                 // first of 4 consecutive voxels
    int b = i / DHW;
    int s = i - b * DHW;            // flat index within [D,H,W]

    const float* fbase = flow + (size_t)b * 3 * DHW;
    const float* sbase = src + (size_t)b * DHW;

    float4 fld = *reinterpret_cast<const float4*>(fbase + s);
    float4 flh = *reinterpret_cast<const float4*>(fbase + DHW + s);
    float4 flw = *reinterpret_cast<const float4*>(fbase + 2 * DHW + s);

    // W=224 divisible by 4 -> the 4 voxels share one (d,h) row.
    int w = s % WW;
    int t = s / WW;
    int h = t % HH;
    int d = t / HH;
    float df = (float)d, hf = (float)h, wf = (float)w;

    float fdv[4] = {fld.x, fld.y, fld.z, fld.w};
    float fhv[4] = {flh.x, flh.y, flh.z, flh.w};
    float fwv[4] = {flw.x, flw.y, flw.z, flw.w};

    float res[4];
    #pragma unroll
    for (int k = 0; k < 4; ++k) {
        res[k] = trilerp(sbase, df + fdv[k], hf + fhv[k],
                         wf + (float)k + fwv[k]);
    }

    float4 o = make_float4(res[0], res[1], res[2], res[3]);
    *reinterpret_cast<float4*>(out + (size_t)i) = o;
}

extern "C" void kernel_launch(void* const* d_in, const int* in_sizes, int n_in,
                              void* d_out, int out_size, void* d_ws, size_t ws_size,
                              hipStream_t stream) {
    const float* src  = (const float*)d_in[0];
    const float* flow = (const float*)d_in[1];
    float* out = (float*)d_out;

    warp3d_kernel<<<NWG, BLOCK, 0, stream>>>(src, flow, out);
}

// Round 5
// 185.379 us; speedup vs baseline: 2.1959x; 1.1409x over previous
//
#include <hip/hip_runtime.h>

// 3D trilinear warp (grid_sample, align_corners=True equivalent, zeros padding)
// src:  [B=2, C=1, D=160, H=192, W=224] f32
// flow: [B=2, 3,   D,     H,     W    ] f32  (d,h,w voxel displacements)
// out:  [B=2, C=1, D,     H,     W    ] f32

#define DD 160
#define HH 192
#define WW 224
constexpr int DHW = DD * HH * WW;          // 6,881,280 (divisible by 4)
constexpr int TOTAL4 = 2 * DHW / 4;        // groups of 4 voxels
constexpr int BLOCK = 256;
constexpr int NWG = TOTAL4 / BLOCK;        // 13440, divisible by 8
constexpr int NXCD = 8;
constexpr int CHUNK = NWG / NXCD;          // 1680 blocks per XCD chunk

// Native clang vector type: __builtin_nontemporal_* rejects HIP_vector_type.
typedef float vfloat4 __attribute__((ext_vector_type(4)));

// Compute the 8 tap offsets + 8 weights for one voxel. Branchless: validity
// folded into per-dimension weights, indices clamped (matches reference's
// clip + valid-mask semantics exactly).
__device__ __forceinline__ void prep(float cd, float ch, float cw,
                                     int* __restrict__ o, float* __restrict__ wt) {
    float d0f = floorf(cd), h0f = floorf(ch), w0f = floorf(cw);
    float fd = cd - d0f, fh = ch - h0f, fw = cw - w0f;
    int d0 = (int)d0f, h0 = (int)h0f, w0 = (int)w0f;
    int d1 = d0 + 1, h1 = h0 + 1, w1 = w0 + 1;

    float wd0 = (1.0f - fd) * ((unsigned)d0 < (unsigned)DD ? 1.0f : 0.0f);
    float wd1 = fd          * ((unsigned)d1 < (unsigned)DD ? 1.0f : 0.0f);
    float wh0 = (1.0f - fh) * ((unsigned)h0 < (unsigned)HH ? 1.0f : 0.0f);
    float wh1 = fh          * ((unsigned)h1 < (unsigned)HH ? 1.0f : 0.0f);
    float ww0 = (1.0f - fw) * ((unsigned)w0 < (unsigned)WW ? 1.0f : 0.0f);
    float ww1 = fw          * ((unsigned)w1 < (unsigned)WW ? 1.0f : 0.0f);

    int d0c = min(max(d0, 0), DD - 1), d1c = min(max(d1, 0), DD - 1);
    int h0c = min(max(h0, 0), HH - 1), h1c = min(max(h1, 0), HH - 1);
    int w0c = min(max(w0, 0), WW - 1), w1c = min(max(w1, 0), WW - 1);

    int r00 = (d0c * HH + h0c) * WW, r01 = (d0c * HH + h1c) * WW;
    int r10 = (d1c * HH + h0c) * WW, r11 = (d1c * HH + h1c) * WW;
    o[0] = r00 + w0c; o[1] = r00 + w1c; o[2] = r01 + w0c; o[3] = r01 + w1c;
    o[4] = r10 + w0c; o[5] = r10 + w1c; o[6] = r11 + w0c; o[7] = r11 + w1c;

    float wdh00 = wd0 * wh0, wdh01 = wd0 * wh1;
    float wdh10 = wd1 * wh0, wdh11 = wd1 * wh1;
    wt[0] = wdh00 * ww0; wt[1] = wdh00 * ww1;
    wt[2] = wdh01 * ww0; wt[3] = wdh01 * ww1;
    wt[4] = wdh10 * ww0; wt[5] = wdh10 * ww1;
    wt[6] = wdh11 * ww0; wt[7] = wdh11 * ww1;
}

__global__ __launch_bounds__(256) void warp3d_kernel(
    const float* __restrict__ src, const float* __restrict__ flow,
    float* __restrict__ out) {
    // XCD-aware swizzle: consecutive work chunks stay on one XCD so the
    // src slab (+halo) lives in that XCD's private 4 MB L2.
    int bid = blockIdx.x;                 // 0..NWG-1, dispatched i%8 -> XCD
    int xcd = bid % NXCD;
    int idx = bid / NXCD;
    int wg  = xcd * CHUNK + idx;          // contiguous chunk per XCD

    int i4 = wg * BLOCK + threadIdx.x;
    int i = i4 * 4;                 // first of 4 consecutive voxels
    int b = i / DHW;
    int s = i - b * DHW;            // flat index within [D,H,W]

    const float* fbase = flow + (size_t)b * 3 * DHW;
    const float* sbase = src + (size_t)b * DHW;

    // Flow is streamed exactly once: nontemporal keeps L1/L2 free for the
    // src gather working set (3.4 MB slab per XCD vs 4 MB L2).
    vfloat4 fld = __builtin_nontemporal_load(
        reinterpret_cast<const vfloat4*>(fbase + s));
    vfloat4 flh = __builtin_nontemporal_load(
        reinterpret_cast<const vfloat4*>(fbase + DHW + s));
    vfloat4 flw = __builtin_nontemporal_load(
        reinterpret_cast<const vfloat4*>(fbase + 2 * DHW + s));

    // W=224 divisible by 4 -> the 4 voxels share one (d,h) row.
    int w = s % WW;
    int t = s / WW;
    int h = t % HH;
    int d = t / HH;
    float df = (float)d, hf = (float)h, wf = (float)w;

    float fdv[4] = {fld.x, fld.y, fld.z, fld.w};
    float fhv[4] = {flh.x, flh.y, flh.z, flh.w};
    float fwv[4] = {flw.x, flw.y, flw.z, flw.w};

    float res[4];
    // 2-voxel batches: 16 tap offsets computed, 16 loads issued together
    // (one vmcnt drain per batch instead of per-tap serialization).
    #pragma unroll
    for (int q = 0; q < 2; ++q) {
        int o[2][8]; float wt[2][8]; float v[2][8];
        #pragma unroll
        for (int j = 0; j < 2; ++j) {
            int k = q * 2 + j;
            prep(df + fdv[k], hf + fhv[k], wf + (float)k + fwv[k], o[j], wt[j]);
        }
        #pragma unroll
        for (int j = 0; j < 2; ++j) {
            #pragma unroll
            for (int tp = 0; tp < 8; ++tp) v[j][tp] = sbase[o[j][tp]];
        }
        #pragma unroll
        for (int j = 0; j < 2; ++j) {
            float a = 0.0f;
            #pragma unroll
            for (int tp = 0; tp < 8; ++tp) a += v[j][tp] * wt[j][tp];
            res[q * 2 + j] = a;
        }
    }

    vfloat4 o4 = {res[0], res[1], res[2], res[3]};
    // Output is written once, never read back: nontemporal store.
    __builtin_nontemporal_store(o4, reinterpret_cast<vfloat4*>(out + (size_t)i));
}

extern "C" void kernel_launch(void* const* d_in, const int* in_sizes, int n_in,
                              void* d_out, int out_size, void* d_ws, size_t ws_size,
                              hipStream_t stream) {
    const float* src  = (const float*)d_in[0];
    const float* flow = (const float*)d_in[1];
    float* out = (float*)d_out;

    warp3d_kernel<<<NWG, BLOCK, 0, stream>>>(src, flow, out);
}

// Round 6
// 127.010 us; speedup vs baseline: 3.2051x; 1.4596x over previous
//
#include <hip/hip_runtime.h>

// 3D trilinear warp (grid_sample, align_corners=True equivalent, zeros padding)
// src:  [B=2, C=1, D=160, H=192, W=224] f32
// flow: [B=2, 3,   D,     H,     W    ] f32  (d,h,w voxel displacements)
// out:  [B=2, C=1, D,     H,     W    ] f32

#define DD 160
#define HH 192
#define WW 224
constexpr int DHW = DD * HH * WW;          // 6,881,280
constexpr int BLOCK = 256;
// Brick decomposition: block = 8d x 8h x 16w = 1024 voxels (4 voxels/thread).
constexpr int DT = DD / 8;                 // 20
constexpr int HT = HH / 8;                 // 24
constexpr int WT = WW / 16;                // 14
constexpr int BRICKS_PER_B = DT * HT * WT; // 6720
constexpr int NWG = 2 * BRICKS_PER_B;      // 13440, divisible by 8
constexpr int NXCD = 8;
constexpr int CHUNK = NWG / NXCD;          // 1680

// Native clang vector types (__builtin_nontemporal_* rejects HIP_vector_type).
typedef float vfloat4 __attribute__((ext_vector_type(4)));
// align(4): w-pair loads are only dword-aligned; gfx950 supports unaligned
// global dwordx2.
typedef float vfloat2 __attribute__((ext_vector_type(2), aligned(4)));

// Per-voxel tap prep. Branchless: validity folded into weights, indices
// clamped (matches reference clip+valid semantics). The two w-taps are read
// as one float2 at wb=clamp(w0,0,W-2); sel0/sel1 pick the element for each
// tap (whenever the pick is ambiguous the corresponding weight is zero).
__device__ __forceinline__ void prep(float cd, float ch, float cw,
                                     int* __restrict__ o, int& sel0, int& sel1,
                                     float* __restrict__ wt) {
    float d0f = floorf(cd), h0f = floorf(ch), w0f = floorf(cw);
    float fd = cd - d0f, fh = ch - h0f, fw = cw - w0f;
    int d0 = (int)d0f, h0 = (int)h0f, w0 = (int)w0f;
    int d1 = d0 + 1, h1 = h0 + 1, w1 = w0 + 1;

    float wd0 = (1.0f - fd) * ((unsigned)d0 < (unsigned)DD ? 1.0f : 0.0f);
    float wd1 = fd          * ((unsigned)d1 < (unsigned)DD ? 1.0f : 0.0f);
    float wh0 = (1.0f - fh) * ((unsigned)h0 < (unsigned)HH ? 1.0f : 0.0f);
    float wh1 = fh          * ((unsigned)h1 < (unsigned)HH ? 1.0f : 0.0f);
    float ww0 = (1.0f - fw) * ((unsigned)w0 < (unsigned)WW ? 1.0f : 0.0f);
    float ww1 = fw          * ((unsigned)w1 < (unsigned)WW ? 1.0f : 0.0f);

    int d0c = min(max(d0, 0), DD - 1), d1c = min(max(d1, 0), DD - 1);
    int h0c = min(max(h0, 0), HH - 1), h1c = min(max(h1, 0), HH - 1);
    int wb  = min(max(w0, 0), WW - 2);
    sel0 = min(max(w0, 0), WW - 1) - wb;   // 0 or 1
    sel1 = min(max(w1, 0), WW - 1) - wb;   // 0 or 1

    o[0] = (d0c * HH + h0c) * WW + wb;
    o[1] = (d0c * HH + h1c) * WW + wb;
    o[2] = (d1c * HH + h0c) * WW + wb;
    o[3] = (d1c * HH + h1c) * WW + wb;

    float wdh00 = wd0 * wh0, wdh01 = wd0 * wh1;
    float wdh10 = wd1 * wh0, wdh11 = wd1 * wh1;
    wt[0] = wdh00 * ww0; wt[1] = wdh00 * ww1;
    wt[2] = wdh01 * ww0; wt[3] = wdh01 * ww1;
    wt[4] = wdh10 * ww0; wt[5] = wdh10 * ww1;
    wt[6] = wdh11 * ww0; wt[7] = wdh11 * ww1;
}

__global__ __launch_bounds__(256) void warp3d_kernel(
    const float* __restrict__ src, const float* __restrict__ flow,
    float* __restrict__ out) {
    // XCD-aware swizzle: contiguous brick ranges per XCD.
    int bid = blockIdx.x;
    int xcd = bid & 7;
    int idx = bid >> 3;
    int wg  = xcd * CHUNK + idx;

    int b  = wg / BRICKS_PER_B;
    int r  = wg - b * BRICKS_PER_B;
    int dt = r / (HT * WT);
    int r2 = r - dt * (HT * WT);
    int ht = r2 / WT;
    int wtile = r2 - ht * WT;

    // Wave = 4d x 4h x 16w sub-brick: the wave's whole tap footprint is a
    // ~15 KB window that fits L1 for the duration of the gather burst.
    int tid  = threadIdx.x;
    int wave = tid >> 6;
    int lane = tid & 63;
    int d = dt * 8 + (wave >> 1) * 4 + (lane >> 4);
    int h = ht * 8 + (wave & 1) * 4 + ((lane >> 2) & 3);
    int w = wtile * 16 + (lane & 3) * 4;

    size_t sOff = (size_t)(d * HH + h) * WW + w;
    const float* fbase = flow + (size_t)b * 3 * DHW + sOff;
    const float* sbase = src + (size_t)b * DHW;

    // Flow streamed once: nontemporal keeps L1/L2 for the src working set.
    vfloat4 fld = __builtin_nontemporal_load(
        reinterpret_cast<const vfloat4*>(fbase));
    vfloat4 flh = __builtin_nontemporal_load(
        reinterpret_cast<const vfloat4*>(fbase + DHW));
    vfloat4 flw = __builtin_nontemporal_load(
        reinterpret_cast<const vfloat4*>(fbase + 2 * DHW));

    float df = (float)d, hf = (float)h, wf = (float)w;
    float fdv[4] = {fld.x, fld.y, fld.z, fld.w};
    float fhv[4] = {flh.x, flh.y, flh.z, flh.w};
    float fwv[4] = {flw.x, flw.y, flw.z, flw.w};

    // All 4 voxels fully batched: 16 addresses+weights, then 16 float2 loads
    // in flight under one drain, then the FMA trees.
    int o[4][4]; int s0[4], s1[4]; float wt[4][8];
    #pragma unroll
    for (int k = 0; k < 4; ++k)
        prep(df + fdv[k], hf + fhv[k], wf + (float)k + fwv[k],
             o[k], s0[k], s1[k], wt[k]);

    vfloat2 p[4][4];
    #pragma unroll
    for (int k = 0; k < 4; ++k)
        #pragma unroll
        for (int j = 0; j < 4; ++j)
            p[k][j] = *reinterpret_cast<const vfloat2*>(sbase + o[k][j]);

    float res[4];
    #pragma unroll
    for (int k = 0; k < 4; ++k) {
        float a = 0.0f;
        #pragma unroll
        for (int j = 0; j < 4; ++j) {
            float va = s0[k] ? p[k][j].y : p[k][j].x;
            float vb = s1[k] ? p[k][j].y : p[k][j].x;
            a += wt[k][2 * j] * va + wt[k][2 * j + 1] * vb;
        }
        res[k] = a;
    }

    vfloat4 o4 = {res[0], res[1], res[2], res[3]};
    __builtin_nontemporal_store(o4, reinterpret_cast<vfloat4*>(
        out + (size_t)b * DHW + sOff));
}

extern "C" void kernel_launch(void* const* d_in, const int* in_sizes, int n_in,
                              void* d_out, int out_size, void* d_ws, size_t ws_size,
                              hipStream_t stream) {
    const float* src  = (const float*)d_in[0];
    const float* flow = (const float*)d_in[1];
    float* out = (float*)d_out;

    warp3d_kernel<<<NWG, BLOCK, 0, stream>>>(src, flow, out);
}

// Round 7
// 82.428 us; speedup vs baseline: 4.9386x; 1.5409x over previous
//
#include <hip/hip_runtime.h>

// 3D trilinear warp (grid_sample, align_corners=True equivalent, zeros padding)
// src:  [B=2, C=1, D=160, H=192, W=224] f32
// flow: [B=2, 3,   D,     H,     W    ] f32  (d,h,w voxel displacements)
// out:  [B=2, C=1, D,     H,     W    ] f32
//
// Strategy: per-block LDS staging of the src brick + halo-4 (coalesced),
// gathers served from LDS; rare out-of-halo taps fall back to global.

#define DD 160
#define HH 192
#define WW 224
constexpr int DHW = DD * HH * WW;          // 6,881,280
constexpr int BLOCK = 256;
// Brick: 8d x 8h x 16w = 1024 voxels (4 voxels/thread).
constexpr int DT = DD / 8;                 // 20
constexpr int HT = HH / 8;                 // 24
constexpr int WT = WW / 16;                // 14
constexpr int BRICKS_PER_B = DT * HT * WT; // 6720
constexpr int NWG = 2 * BRICKS_PER_B;      // 13440, divisible by 8
constexpr int NXCD = 8;
constexpr int CHUNK = NWG / NXCD;          // 1680

// Staged region: halo 4 both sides. d,h: 8+8=16; w: 16+8=24 (stride 24).
constexpr int RD = 16, RH = 16, RWS = 24;
constexpr int TILE_N = RD * RH * RWS;      // 6144 floats = 24 KB -> 6 blk/CU

typedef float vfloat4 __attribute__((ext_vector_type(4)));

// Global fallback tap (rare): branchless, clamped indices, validity folded
// into weights — bit-identical to the LDS path's semantics.
__device__ __forceinline__ float trilerp_global(const float* __restrict__ sbase,
                                                float cd, float ch, float cw) {
    float d0f = floorf(cd), h0f = floorf(ch), w0f = floorf(cw);
    float fd = cd - d0f, fh = ch - h0f, fw = cw - w0f;
    int d0 = (int)d0f, h0 = (int)h0f, w0 = (int)w0f;
    int d1 = d0 + 1, h1 = h0 + 1, w1 = w0 + 1;

    float wd0 = (1.0f - fd) * ((unsigned)d0 < (unsigned)DD ? 1.0f : 0.0f);
    float wd1 = fd          * ((unsigned)d1 < (unsigned)DD ? 1.0f : 0.0f);
    float wh0 = (1.0f - fh) * ((unsigned)h0 < (unsigned)HH ? 1.0f : 0.0f);
    float wh1 = fh          * ((unsigned)h1 < (unsigned)HH ? 1.0f : 0.0f);
    float ww0 = (1.0f - fw) * ((unsigned)w0 < (unsigned)WW ? 1.0f : 0.0f);
    float ww1 = fw          * ((unsigned)w1 < (unsigned)WW ? 1.0f : 0.0f);

    int d0c = min(max(d0, 0), DD - 1), d1c = min(max(d1, 0), DD - 1);
    int h0c = min(max(h0, 0), HH - 1), h1c = min(max(h1, 0), HH - 1);
    int w0c = min(max(w0, 0), WW - 1), w1c = min(max(w1, 0), WW - 1);

    const float* p00 = sbase + (d0c * HH + h0c) * WW;
    const float* p01 = sbase + (d0c * HH + h1c) * WW;
    const float* p10 = sbase + (d1c * HH + h0c) * WW;
    const float* p11 = sbase + (d1c * HH + h1c) * WW;

    return wd0 * (wh0 * (ww0 * p00[w0c] + ww1 * p00[w1c]) +
                  wh1 * (ww0 * p01[w0c] + ww1 * p01[w1c])) +
           wd1 * (wh0 * (ww0 * p10[w0c] + ww1 * p10[w1c]) +
                  wh1 * (ww0 * p11[w0c] + ww1 * p11[w1c]));
}

__global__ __launch_bounds__(256) void warp3d_kernel(
    const float* __restrict__ src, const float* __restrict__ flow,
    float* __restrict__ out) {
    __shared__ float tile[TILE_N];

    // XCD-aware swizzle: contiguous brick ranges per XCD.
    int bid = blockIdx.x;
    int wg  = (bid & 7) * CHUNK + (bid >> 3);

    int b  = wg / BRICKS_PER_B;
    int r  = wg - b * BRICKS_PER_B;
    int dt = r / (HT * WT);
    int r2 = r - dt * (HT * WT);
    int ht = r2 / WT;
    int wtile = r2 - ht * WT;

    int dB = dt * 8, hB = ht * 8, wB = wtile * 16;
    int dB4 = dB - 4, hB4 = hB - 4, wB4 = wB - 4;

    const float* sbase = src + (size_t)b * DHW;

    // Output voxel mapping (wave = 4d x 4h x 16w sub-brick).
    int tid  = threadIdx.x;
    int wave = tid >> 6;
    int lane = tid & 63;
    int d = dB + (wave >> 1) * 4 + (lane >> 4);
    int h = hB + (wave & 1) * 4 + ((lane >> 2) & 3);
    int w = wB + (lane & 3) * 4;

    size_t sOff = (size_t)(d * HH + h) * WW + w;
    const float* fb = flow + (size_t)b * 3 * DHW + sOff;
    // Issue flow loads first; they drain while staging proceeds.
    vfloat4 fld = *reinterpret_cast<const vfloat4*>(fb);
    vfloat4 flh = *reinterpret_cast<const vfloat4*>(fb + DHW);
    vfloat4 flw = *reinterpret_cast<const vfloat4*>(fb + 2 * DHW);

    // ---- Stage src brick + halo into LDS (coalesced) ----
    // 256 rows (16d x 16h), 24 floats each; 8 threads/row, chunks c<6 active.
    // Row sources use clamped (d,h) so staged values == global-path values.
    int srow = tid >> 3;
    int c    = tid & 7;
    bool wedge = (wtile == 0) | (wtile == WT - 1);  // w-halo crosses volume
    #pragma unroll
    for (int p = 0; p < 8; ++p) {
        int rr = srow + p * 32;            // 0..255
        int ld = rr >> 4, lh = rr & 15;
        int dg = min(max(dB4 + ld, 0), DD - 1);
        int hg = min(max(hB4 + lh, 0), HH - 1);
        const float* grow = sbase + (size_t)(dg * HH + hg) * WW;
        if (c < 6) {
            int wg0 = wB4 + 4 * c;         // 16B-aligned for interior tiles
            vfloat4 v;
            if (!wedge) {
                v = *reinterpret_cast<const vfloat4*>(grow + wg0);
            } else {
                v.x = grow[min(max(wg0 + 0, 0), WW - 1)];
                v.y = grow[min(max(wg0 + 1, 0), WW - 1)];
                v.z = grow[min(max(wg0 + 2, 0), WW - 1)];
                v.w = grow[min(max(wg0 + 3, 0), WW - 1)];
            }
            *reinterpret_cast<vfloat4*>(&tile[rr * RWS + 4 * c]) = v;
        }
    }
    __syncthreads();

    float df = (float)d, hf = (float)h, wf = (float)w;
    float fdv[4] = {fld.x, fld.y, fld.z, fld.w};
    float fhv[4] = {flh.x, flh.y, flh.z, flh.w};
    float fwv[4] = {flw.x, flw.y, flw.z, flw.w};

    int   base[4];
    float wt8[4][8];
    bool  allin = true;
    #pragma unroll
    for (int k = 0; k < 4; ++k) {
        float cd = df + fdv[k], ch = hf + fhv[k], cw = wf + (float)k + fwv[k];
        float d0f = floorf(cd), h0f = floorf(ch), w0f = floorf(cw);
        float fd = cd - d0f, fh = ch - h0f, fw = cw - w0f;
        int d0 = (int)d0f, h0 = (int)h0f, w0 = (int)w0f;

        float wd0 = (1.0f - fd) * ((unsigned)d0 < (unsigned)DD ? 1.0f : 0.0f);
        float wd1 = fd       * ((unsigned)(d0 + 1) < (unsigned)DD ? 1.0f : 0.0f);
        float wh0 = (1.0f - fh) * ((unsigned)h0 < (unsigned)HH ? 1.0f : 0.0f);
        float wh1 = fh       * ((unsigned)(h0 + 1) < (unsigned)HH ? 1.0f : 0.0f);
        float ww0 = (1.0f - fw) * ((unsigned)w0 < (unsigned)WW ? 1.0f : 0.0f);
        float ww1 = fw       * ((unsigned)(w0 + 1) < (unsigned)WW ? 1.0f : 0.0f);

        int rd = d0 - dB4, rh = h0 - hB4, rw = w0 - wB4;
        // need rd,rd+1 <= 15; rh,rh+1 <= 15; rw,rw+1 <= 23
        allin = allin & ((unsigned)rd < 15u) & ((unsigned)rh < 15u)
                      & ((unsigned)rw < 23u);
        base[k] = (rd * RH + rh) * RWS + rw;

        float a = wd0 * wh0, bq = wd0 * wh1, cq = wd1 * wh0, dq = wd1 * wh1;
        wt8[k][0] = a * ww0;  wt8[k][1] = a * ww1;
        wt8[k][2] = bq * ww0; wt8[k][3] = bq * ww1;
        wt8[k][4] = cq * ww0; wt8[k][5] = cq * ww1;
        wt8[k][6] = dq * ww0; wt8[k][7] = dq * ww1;
    }

    float res[4];
    if (allin) {
        // 32 LDS reads (16 adjacent pairs), all issued together.
        #pragma unroll
        for (int k = 0; k < 4; ++k) {
            int b0 = base[k];
            float v0 = tile[b0],                v1 = tile[b0 + 1];
            float v2 = tile[b0 + RWS],          v3 = tile[b0 + RWS + 1];
            float v4 = tile[b0 + RH * RWS],     v5 = tile[b0 + RH * RWS + 1];
            float v6 = tile[b0 + RH * RWS + RWS];
            float v7 = tile[b0 + RH * RWS + RWS + 1];
            res[k] = wt8[k][0] * v0 + wt8[k][1] * v1 + wt8[k][2] * v2 +
                     wt8[k][3] * v3 + wt8[k][4] * v4 + wt8[k][5] * v5 +
                     wt8[k][6] * v6 + wt8[k][7] * v7;
        }
    } else {
        // Rare (flow beyond halo): recompute fully from global.
        #pragma unroll
        for (int k = 0; k < 4; ++k)
            res[k] = trilerp_global(sbase, df + fdv[k], hf + fhv[k],
                                    wf + (float)k + fwv[k]);
    }

    vfloat4 o4 = {res[0], res[1], res[2], res[3]};
    *reinterpret_cast<vfloat4*>(out + (size_t)b * DHW + sOff) = o4;
}

extern "C" void kernel_launch(void* const* d_in, const int* in_sizes, int n_in,
                              void* d_out, int out_size, void* d_ws, size_t ws_size,
                              hipStream_t stream) {
    const float* src  = (const float*)d_in[0];
    const float* flow = (const float*)d_in[1];
    float* out = (float*)d_out;

    warp3d_kernel<<<NWG, BLOCK, 0, stream>>>(src, flow, out);
}

// Round 8
// 81.287 us; speedup vs baseline: 5.0079x; 1.0140x over previous
//
#include <hip/hip_runtime.h>

// 3D trilinear warp (grid_sample, align_corners=True equivalent, zeros padding)
// src:  [B=2, C=1, D=160, H=192, W=224] f32
// flow: [B=2, 3,   D,     H,     W    ] f32  (d,h,w voxel displacements)
// out:  [B=2, C=1, D,     H,     W    ] f32
//
// LDS-staged gathers: block stages src brick + halo-4 (coalesced), taps read
// from LDS. Stride padded to 25 floats (d-stride 400 % 32 = 16, h-stride 25
// spans all banks) to kill the 4-way d-group bank conflicts of stride 24.
// Interior blocks take a mask-free 7-lerp path; edge blocks keep masked
// weights; per-lane beyond-halo flow falls back to global trilerp.

#define DD 160
#define HH 192
#define WW 224
constexpr int DHW = DD * HH * WW;          // 6,881,280
constexpr int BLOCK = 256;
// Brick: 8d x 8h x 16w = 1024 voxels (4 voxels/thread).
constexpr int DT = DD / 8;                 // 20
constexpr int HT = HH / 8;                 // 24
constexpr int WT = WW / 16;                // 14
constexpr int BRICKS_PER_B = DT * HT * WT; // 6720
constexpr int NWG = 2 * BRICKS_PER_B;      // 13440, divisible by 8
constexpr int NXCD = 8;
constexpr int CHUNK = NWG / NXCD;          // 1680

// Staged region: halo 4 each side. Extent d,h: 16; w: 24. Row stride 25.
constexpr int RD = 16, RH = 16, RWE = 24, RWP = 25;
constexpr int TILE_N = RD * RH * RWP;      // 6400 floats = 25.6 KB -> 6 blk/CU

typedef float vfloat4 __attribute__((ext_vector_type(4)));

// Global fallback tap (rare): branchless, clamped, validity in weights.
__device__ __forceinline__ float trilerp_global(const float* __restrict__ sbase,
                                                float cd, float ch, float cw) {
    float d0f = floorf(cd), h0f = floorf(ch), w0f = floorf(cw);
    float fd = cd - d0f, fh = ch - h0f, fw = cw - w0f;
    int d0 = (int)d0f, h0 = (int)h0f, w0 = (int)w0f;
    int d1 = d0 + 1, h1 = h0 + 1, w1 = w0 + 1;

    float wd0 = (1.0f - fd) * ((unsigned)d0 < (unsigned)DD ? 1.0f : 0.0f);
    float wd1 = fd          * ((unsigned)d1 < (unsigned)DD ? 1.0f : 0.0f);
    float wh0 = (1.0f - fh) * ((unsigned)h0 < (unsigned)HH ? 1.0f : 0.0f);
    float wh1 = fh          * ((unsigned)h1 < (unsigned)HH ? 1.0f : 0.0f);
    float ww0 = (1.0f - fw) * ((unsigned)w0 < (unsigned)WW ? 1.0f : 0.0f);
    float ww1 = fw          * ((unsigned)w1 < (unsigned)WW ? 1.0f : 0.0f);

    int d0c = min(max(d0, 0), DD - 1), d1c = min(max(d1, 0), DD - 1);
    int h0c = min(max(h0, 0), HH - 1), h1c = min(max(h1, 0), HH - 1);
    int w0c = min(max(w0, 0), WW - 1), w1c = min(max(w1, 0), WW - 1);

    const float* p00 = sbase + (d0c * HH + h0c) * WW;
    const float* p01 = sbase + (d0c * HH + h1c) * WW;
    const float* p10 = sbase + (d1c * HH + h0c) * WW;
    const float* p11 = sbase + (d1c * HH + h1c) * WW;

    return wd0 * (wh0 * (ww0 * p00[w0c] + ww1 * p00[w1c]) +
                  wh1 * (ww0 * p01[w0c] + ww1 * p01[w1c])) +
           wd1 * (wh0 * (ww0 * p10[w0c] + ww1 * p10[w1c]) +
                  wh1 * (ww0 * p11[w0c] + ww1 * p11[w1c]));
}

__global__ __launch_bounds__(256) void warp3d_kernel(
    const float* __restrict__ src, const float* __restrict__ flow,
    float* __restrict__ out) {
    __shared__ float tile[TILE_N];

    // XCD-aware swizzle: contiguous brick ranges per XCD.
    int bid = blockIdx.x;
    int wg  = (bid & 7) * CHUNK + (bid >> 3);

    int b  = wg / BRICKS_PER_B;
    int r  = wg - b * BRICKS_PER_B;
    int dt = r / (HT * WT);
    int r2 = r - dt * (HT * WT);
    int ht = r2 / WT;
    int wtile = r2 - ht * WT;

    int dB = dt * 8, hB = ht * 8, wB = wtile * 16;
    int dB4 = dB - 4, hB4 = hB - 4, wB4 = wB - 4;

    // Region strictly inside the volume -> no validity masks needed.
    bool interior = (dt >= 1) & (dt <= DT - 2) & (ht >= 1) & (ht <= HT - 2)
                  & (wtile >= 1) & (wtile <= WT - 2);

    const float* sbase = src + (size_t)b * DHW;

    // Output voxel mapping (wave = 4d x 4h x 16w sub-brick).
    int tid  = threadIdx.x;
    int wave = tid >> 6;
    int lane = tid & 63;
    int d = dB + (wave >> 1) * 4 + (lane >> 4);
    int h = hB + (wave & 1) * 4 + ((lane >> 2) & 3);
    int w = wB + (lane & 3) * 4;

    size_t sOff = (size_t)(d * HH + h) * WW + w;
    const float* fb = flow + (size_t)b * 3 * DHW + sOff;
    // Issue flow loads first; they drain while staging proceeds.
    vfloat4 fld = *reinterpret_cast<const vfloat4*>(fb);
    vfloat4 flh = *reinterpret_cast<const vfloat4*>(fb + DHW);
    vfloat4 flw = *reinterpret_cast<const vfloat4*>(fb + 2 * DHW);

    // ---- Stage src brick + halo into LDS (coalesced reads) ----
    // 256 rows (16d x 16h) x 24 floats; 8 threads/row, chunks c<6 active.
    int srow = tid >> 3;
    int c    = tid & 7;
    bool wedge = (wtile == 0) | (wtile == WT - 1);  // w-halo crosses volume
    #pragma unroll
    for (int p = 0; p < 8; ++p) {
        int rr = srow + p * 32;            // 0..255
        int ld = rr >> 4, lh = rr & 15;
        int dg = min(max(dB4 + ld, 0), DD - 1);
        int hg = min(max(hB4 + lh, 0), HH - 1);
        const float* grow = sbase + (size_t)(dg * HH + hg) * WW;
        if (c < 6) {
            int wg0 = wB4 + 4 * c;         // 16B-aligned for interior tiles
            vfloat4 v;
            if (!wedge) {
                v = *reinterpret_cast<const vfloat4*>(grow + wg0);
            } else {
                v.x = grow[min(max(wg0 + 0, 0), WW - 1)];
                v.y = grow[min(max(wg0 + 1, 0), WW - 1)];
                v.z = grow[min(max(wg0 + 2, 0), WW - 1)];
                v.w = grow[min(max(wg0 + 3, 0), WW - 1)];
            }
            float* dst = &tile[rr * RWP + 4 * c];   // stride 25: scalar writes
            dst[0] = v.x; dst[1] = v.y; dst[2] = v.z; dst[3] = v.w;
        }
    }
    __syncthreads();

    float df = (float)d, hf = (float)h, wf = (float)w;
    float fdv[4] = {fld.x, fld.y, fld.z, fld.w};
    float fhv[4] = {flh.x, flh.y, flh.z, flh.w};
    float fwv[4] = {flw.x, flw.y, flw.z, flw.w};

    float cdv[4], chv[4], cwv[4];
    float fdq[4], fhq[4], fwq[4];
    int   base[4];
    bool  okv[4];
    #pragma unroll
    for (int k = 0; k < 4; ++k) {
        float cd = df + fdv[k], ch = hf + fhv[k], cw = wf + (float)k + fwv[k];
        cdv[k] = cd; chv[k] = ch; cwv[k] = cw;
        float d0f = floorf(cd), h0f = floorf(ch), w0f = floorf(cw);
        fdq[k] = cd - d0f; fhq[k] = ch - h0f; fwq[k] = cw - w0f;
        int rd = (int)d0f - dB4, rh = (int)h0f - hB4, rw = (int)w0f - wB4;
        okv[k] = ((unsigned)rd < (unsigned)(RD - 1)) &
                 ((unsigned)rh < (unsigned)(RH - 1)) &
                 ((unsigned)rw < (unsigned)(RWE - 1));
        base[k] = (rd * RH + rh) * RWP + rw;
    }
    bool allin = okv[0] & okv[1] & okv[2] & okv[3];

    float res[4];
    if (allin) {
        if (interior) {
            // Mask-free: 8 LDS taps + 7-lerp tree per voxel.
            #pragma unroll
            for (int k = 0; k < 4; ++k) {
                int b0 = base[k];
                float fw = fwq[k], fh = fhq[k], fd = fdq[k];
                float v0 = tile[b0],                 v1 = tile[b0 + 1];
                float v2 = tile[b0 + RWP],           v3 = tile[b0 + RWP + 1];
                float v4 = tile[b0 + RH * RWP],      v5 = tile[b0 + RH * RWP + 1];
                float v6 = tile[b0 + RH * RWP + RWP];
                float v7 = tile[b0 + RH * RWP + RWP + 1];
                float x0 = fmaf(fw, v1 - v0, v0);
                float x1 = fmaf(fw, v3 - v2, v2);
                float x2 = fmaf(fw, v5 - v4, v4);
                float x3 = fmaf(fw, v7 - v6, v6);
                float y0 = fmaf(fh, x1 - x0, x0);
                float y1 = fmaf(fh, x3 - x2, x2);
                res[k] = fmaf(fd, y1 - y0, y0);
            }
        } else {
            // Edge block: validity folded into weights (zeros padding).
            #pragma unroll
            for (int k = 0; k < 4; ++k) {
                float cd = cdv[k], ch = chv[k], cw = cwv[k];
                int d0 = (int)floorf(cd), h0 = (int)floorf(ch),
                    w0 = (int)floorf(cw);
                float fd = fdq[k], fh = fhq[k], fw = fwq[k];
                float wd0 = (1.0f - fd) * ((unsigned)d0 < (unsigned)DD ? 1.0f : 0.0f);
                float wd1 = fd    * ((unsigned)(d0 + 1) < (unsigned)DD ? 1.0f : 0.0f);
                float wh0 = (1.0f - fh) * ((unsigned)h0 < (unsigned)HH ? 1.0f : 0.0f);
                float wh1 = fh    * ((unsigned)(h0 + 1) < (unsigned)HH ? 1.0f : 0.0f);
                float ww0 = (1.0f - fw) * ((unsigned)w0 < (unsigned)WW ? 1.0f : 0.0f);
                float ww1 = fw    * ((unsigned)(w0 + 1) < (unsigned)WW ? 1.0f : 0.0f);
                int b0 = base[k];
                float v0 = tile[b0],                 v1 = tile[b0 + 1];
                float v2 = tile[b0 + RWP],           v3 = tile[b0 + RWP + 1];
                float v4 = tile[b0 + RH * RWP],      v5 = tile[b0 + RH * RWP + 1];
                float v6 = tile[b0 + RH * RWP + RWP];
                float v7 = tile[b0 + RH * RWP + RWP + 1];
                float a = wd0 * wh0, bq = wd0 * wh1, cq = wd1 * wh0, dq = wd1 * wh1;
                res[k] = a  * (ww0 * v0 + ww1 * v1) + bq * (ww0 * v2 + ww1 * v3) +
                         cq * (ww0 * v4 + ww1 * v5) + dq * (ww0 * v6 + ww1 * v7);
            }
        }
    } else {
        // Rare (flow beyond halo): recompute fully from global.
        #pragma unroll
        for (int k = 0; k < 4; ++k)
            res[k] = trilerp_global(sbase, cdv[k], chv[k], cwv[k]);
    }

    vfloat4 o4 = {res[0], res[1], res[2], res[3]};
    *reinterpret_cast<vfloat4*>(out + (size_t)b * DHW + sOff) = o4;
}

extern "C" void kernel_launch(void* const* d_in, const int* in_sizes, int n_in,
                              void* d_out, int out_size, void* d_ws, size_t ws_size,
                              hipStream_t stream) {
    const float* src  = (const float*)d_in[0];
    const float* flow = (const float*)d_in[1];
    float* out = (float*)d_out;

    warp3d_kernel<<<NWG, BLOCK, 0, stream>>>(src, flow, out);
}

// Round 9
// 69.460 us; speedup vs baseline: 5.8606x; 1.1703x over previous
//
#include <hip/hip_runtime.h>

// 3D trilinear warp (grid_sample, align_corners=True equivalent, zeros padding)
// src:  [B=2, C=1, D=160, H=192, W=224] f32
// flow: [B=2, 3,   D,     H,     W    ] f32  (d,h,w voxel displacements)
// out:  [B=2, C=1, D,     H,     W    ] f32
//
// LDS-staged gathers. Brick = 16d x 8h x 16w (2048 voxels, 512 threads,
// 4 voxels/thread), halo 4 -> region 24x16x24 @ stride 25 = 38.4 KB LDS,
// 4 blocks/CU = 32 waves = 100% occupancy. Random-gather bank conflicts are
// inherent (~2x min cycles); we hide them with occupancy instead of fighting
// the address pattern (R8 lesson: padding didn't move the conflict count).

#define DD 160
#define HH 192
#define WW 224
constexpr int DHW = DD * HH * WW;          // 6,881,280
constexpr int BLOCK = 512;
// Brick: 16d x 8h x 16w.
constexpr int DT = DD / 16;                // 10
constexpr int HT = HH / 8;                 // 24
constexpr int WT = WW / 16;                // 14
constexpr int BRICKS_PER_B = DT * HT * WT; // 3360
constexpr int NWG = 2 * BRICKS_PER_B;      // 6720, divisible by 8
constexpr int NXCD = 8;
constexpr int CHUNK = NWG / NXCD;          // 840

// Staged region: halo 4 each side. d: 16+8=24; h: 8+8=16; w: 16+8=24, pad 25.
constexpr int RD = 24, RH = 16, RWE = 24, RWP = 25;
constexpr int TILE_N = RD * RH * RWP;      // 9600 floats = 38.4 KB
constexpr int SROWS = RD * RH;             // 384 staging rows
constexpr int SCHUNKS = SROWS * 6;         // 2304 float4 chunks

typedef float vfloat4 __attribute__((ext_vector_type(4)));

// Global fallback tap (rare): branchless, clamped, validity in weights.
__device__ __forceinline__ float trilerp_global(const float* __restrict__ sbase,
                                                float cd, float ch, float cw) {
    float d0f = floorf(cd), h0f = floorf(ch), w0f = floorf(cw);
    float fd = cd - d0f, fh = ch - h0f, fw = cw - w0f;
    int d0 = (int)d0f, h0 = (int)h0f, w0 = (int)w0f;
    int d1 = d0 + 1, h1 = h0 + 1, w1 = w0 + 1;

    float wd0 = (1.0f - fd) * ((unsigned)d0 < (unsigned)DD ? 1.0f : 0.0f);
    float wd1 = fd          * ((unsigned)d1 < (unsigned)DD ? 1.0f : 0.0f);
    float wh0 = (1.0f - fh) * ((unsigned)h0 < (unsigned)HH ? 1.0f : 0.0f);
    float wh1 = fh          * ((unsigned)h1 < (unsigned)HH ? 1.0f : 0.0f);
    float ww0 = (1.0f - fw) * ((unsigned)w0 < (unsigned)WW ? 1.0f : 0.0f);
    float ww1 = fw          * ((unsigned)w1 < (unsigned)WW ? 1.0f : 0.0f);

    int d0c = min(max(d0, 0), DD - 1), d1c = min(max(d1, 0), DD - 1);
    int h0c = min(max(h0, 0), HH - 1), h1c = min(max(h1, 0), HH - 1);
    int w0c = min(max(w0, 0), WW - 1), w1c = min(max(w1, 0), WW - 1);

    const float* p00 = sbase + (d0c * HH + h0c) * WW;
    const float* p01 = sbase + (d0c * HH + h1c) * WW;
    const float* p10 = sbase + (d1c * HH + h0c) * WW;
    const float* p11 = sbase + (d1c * HH + h1c) * WW;

    return wd0 * (wh0 * (ww0 * p00[w0c] + ww1 * p00[w1c]) +
                  wh1 * (ww0 * p01[w0c] + ww1 * p01[w1c])) +
           wd1 * (wh0 * (ww0 * p10[w0c] + ww1 * p10[w1c]) +
                  wh1 * (ww0 * p11[w0c] + ww1 * p11[w1c]));
}

__global__ __launch_bounds__(512, 8) void warp3d_kernel(
    const float* __restrict__ src, const float* __restrict__ flow,
    float* __restrict__ out) {
    __shared__ float tile[TILE_N];

    // XCD-aware swizzle: contiguous brick ranges per XCD.
    int bid = blockIdx.x;
    int wg  = (bid & 7) * CHUNK + (bid >> 3);

    int b  = wg / BRICKS_PER_B;
    int r  = wg - b * BRICKS_PER_B;
    int dt = r / (HT * WT);
    int r2 = r - dt * (HT * WT);
    int ht = r2 / WT;
    int wtile = r2 - ht * WT;

    int dB = dt * 16, hB = ht * 8, wB = wtile * 16;
    int dB4 = dB - 4, hB4 = hB - 4, wB4 = wB - 4;

    // Region strictly inside the volume -> no validity masks needed.
    bool interior = (dt >= 1) & (dt <= DT - 2) & (ht >= 1) & (ht <= HT - 2)
                  & (wtile >= 1) & (wtile <= WT - 2);

    const float* sbase = src + (size_t)b * DHW;

    // Output voxel mapping (wave = 4d x 4h x 16w sub-brick; 8 waves = 16x8).
    int tid  = threadIdx.x;
    int wave = tid >> 6;
    int lane = tid & 63;
    int d = dB + (wave >> 1) * 4 + (lane >> 4);
    int h = hB + (wave & 1) * 4 + ((lane >> 2) & 3);
    int w = wB + (lane & 3) * 4;

    size_t sOff = (size_t)(d * HH + h) * WW + w;
    const float* fb = flow + (size_t)b * 3 * DHW + sOff;
    // Issue flow loads first; they drain while staging proceeds.
    vfloat4 fld = *reinterpret_cast<const vfloat4*>(fb);
    vfloat4 flh = *reinterpret_cast<const vfloat4*>(fb + DHW);
    vfloat4 flw = *reinterpret_cast<const vfloat4*>(fb + 2 * DHW);

    // ---- Stage src region into LDS (coalesced float4 reads) ----
    // 384 rows (24d x 16h) x 24 floats = 2304 float4 chunks, grid-stride.
    bool wedge = (wtile == 0) | (wtile == WT - 1);  // w-halo crosses volume
    for (int u = tid; u < SCHUNKS; u += BLOCK) {
        int row = u / 6;                   // 0..383
        int c   = u - row * 6;             // 0..5
        int ld = row >> 4, lh = row & 15;
        int dg = min(max(dB4 + ld, 0), DD - 1);
        int hg = min(max(hB4 + lh, 0), HH - 1);
        const float* grow = sbase + (size_t)(dg * HH + hg) * WW;
        int wg0 = wB4 + 4 * c;             // 16B-aligned for interior tiles
        vfloat4 v;
        if (!wedge) {
            v = *reinterpret_cast<const vfloat4*>(grow + wg0);
        } else {
            v.x = grow[min(max(wg0 + 0, 0), WW - 1)];
            v.y = grow[min(max(wg0 + 1, 0), WW - 1)];
            v.z = grow[min(max(wg0 + 2, 0), WW - 1)];
            v.w = grow[min(max(wg0 + 3, 0), WW - 1)];
        }
        float* dst = &tile[row * RWP + 4 * c];   // stride 25: scalar writes
        dst[0] = v.x; dst[1] = v.y; dst[2] = v.z; dst[3] = v.w;
    }
    __syncthreads();

    float df = (float)d, hf = (float)h, wf = (float)w;
    float fdv[4] = {fld.x, fld.y, fld.z, fld.w};
    float fhv[4] = {flh.x, flh.y, flh.z, flh.w};
    float fwv[4] = {flw.x, flw.y, flw.z, flw.w};

    float cdv[4], chv[4], cwv[4];
    float fdq[4], fhq[4], fwq[4];
    int   base[4];
    bool  okv[4];
    #pragma unroll
    for (int k = 0; k < 4; ++k) {
        float cd = df + fdv[k], ch = hf + fhv[k], cw = wf + (float)k + fwv[k];
        cdv[k] = cd; chv[k] = ch; cwv[k] = cw;
        float d0f = floorf(cd), h0f = floorf(ch), w0f = floorf(cw);
        fdq[k] = cd - d0f; fhq[k] = ch - h0f; fwq[k] = cw - w0f;
        int rd = (int)d0f - dB4, rh = (int)h0f - hB4, rw = (int)w0f - wB4;
        okv[k] = ((unsigned)rd < (unsigned)(RD - 1)) &
                 ((unsigned)rh < (unsigned)(RH - 1)) &
                 ((unsigned)rw < (unsigned)(RWE - 1));
        base[k] = (rd * RH + rh) * RWP + rw;
    }
    bool allin = okv[0] & okv[1] & okv[2] & okv[3];

    float res[4];
    if (allin) {
        if (interior) {
            // Mask-free: 8 LDS taps + 7-lerp tree per voxel.
            #pragma unroll
            for (int k = 0; k < 4; ++k) {
                int b0 = base[k];
                float fw = fwq[k], fh = fhq[k], fd = fdq[k];
                float v0 = tile[b0],                 v1 = tile[b0 + 1];
                float v2 = tile[b0 + RWP],           v3 = tile[b0 + RWP + 1];
                float v4 = tile[b0 + RH * RWP],      v5 = tile[b0 + RH * RWP + 1];
                float v6 = tile[b0 + RH * RWP + RWP];
                float v7 = tile[b0 + RH * RWP + RWP + 1];
                float x0 = fmaf(fw, v1 - v0, v0);
                float x1 = fmaf(fw, v3 - v2, v2);
                float x2 = fmaf(fw, v5 - v4, v4);
                float x3 = fmaf(fw, v7 - v6, v6);
                float y0 = fmaf(fh, x1 - x0, x0);
                float y1 = fmaf(fh, x3 - x2, x2);
                res[k] = fmaf(fd, y1 - y0, y0);
            }
        } else {
            // Edge block: validity folded into weights (zeros padding).
            #pragma unroll
            for (int k = 0; k < 4; ++k) {
                float cd = cdv[k], ch = chv[k], cw = cwv[k];
                int d0 = (int)floorf(cd), h0 = (int)floorf(ch),
                    w0 = (int)floorf(cw);
                float fd = fdq[k], fh = fhq[k], fw = fwq[k];
                float wd0 = (1.0f - fd) * ((unsigned)d0 < (unsigned)DD ? 1.0f : 0.0f);
                float wd1 = fd    * ((unsigned)(d0 + 1) < (unsigned)DD ? 1.0f : 0.0f);
                float wh0 = (1.0f - fh) * ((unsigned)h0 < (unsigned)HH ? 1.0f : 0.0f);
                float wh1 = fh    * ((unsigned)(h0 + 1) < (unsigned)HH ? 1.0f : 0.0f);
                float ww0 = (1.0f - fw) * ((unsigned)w0 < (unsigned)WW ? 1.0f : 0.0f);
                float ww1 = fw    * ((unsigned)(w0 + 1) < (unsigned)WW ? 1.0f : 0.0f);
                int b0 = base[k];
                float v0 = tile[b0],                 v1 = tile[b0 + 1];
                float v2 = tile[b0 + RWP],           v3 = tile[b0 + RWP + 1];
                float v4 = tile[b0 + RH * RWP],      v5 = tile[b0 + RH * RWP + 1];
                float v6 = tile[b0 + RH * RWP + RWP];
                float v7 = tile[b0 + RH * RWP + RWP + 1];
                float a = wd0 * wh0, bq = wd0 * wh1, cq = wd1 * wh0, dq = wd1 * wh1;
                res[k] = a  * (ww0 * v0 + ww1 * v1) + bq * (ww0 * v2 + ww1 * v3) +
                         cq * (ww0 * v4 + ww1 * v5) + dq * (ww0 * v6 + ww1 * v7);
            }
        }
    } else {
        // Rare (flow beyond halo): recompute fully from global.
        #pragma unroll
        for (int k = 0; k < 4; ++k)
            res[k] = trilerp_global(sbase, cdv[k], chv[k], cwv[k]);
    }

    vfloat4 o4 = {res[0], res[1], res[2], res[3]};
    *reinterpret_cast<vfloat4*>(out + (size_t)b * DHW + sOff) = o4;
}

extern "C" void kernel_launch(void* const* d_in, const int* in_sizes, int n_in,
                              void* d_out, int out_size, void* d_ws, size_t ws_size,
                              hipStream_t stream) {
    const float* src  = (const float*)d_in[0];
    const float* flow = (const float*)d_in[1];
    float* out = (float*)d_out;

    warp3d_kernel<<<NWG, BLOCK, 0, stream>>>(src, flow, out);
}